// Round 7
// baseline (23733.357 us; speedup 1.0000x reference)
//
#include <hip/hip_runtime.h>

// LSTM: B=8192, T=2048, D=1, H=256, C=10
// Persistent: 256 WGs x 512 threads (1/CU), 32 batch rows per WG.
// Per step: (32x256)@(256x1024) via v_mfma_f32_16x16x32_f16.
// R6 post-mortem: LDS ring double-pays bandwidth (DMA write + ds_read =
// 1.1 MB/step/CU ~ 9-13k cyc) -> this round streams B directly L2->VGPR.
// Residency (8 kk-groups of K=32): kk=0,1 LDS-resident (128 KB), kk=2..7
// reg-streamed via ping-pong Grp bufs sbA/sbB (64 regs). Schedule avoids the
// R5 spill trap: only sbA's next-step load is in flight across the gate
// phase (sbB dead there -> allocator reuses its regs for gate transients);
// sbB's next-step load issues at step entry, latency covered by kk=0,1 LDS
// MFMAs. Stable parity, no manual vmcnt (compiler tracks load->use).
// h single LDS buffer (A-frag order) + 2 lgkm-only barriers/step; x staged
// to LDS every 32 steps. d_ws: 512 KB fp16 B-frags,
// byte off = kk*65536 + s*4096 + t*1024 + lane*16.

#define TT 2048
#define HH 256
#define CC 10

typedef _Float16 half8 __attribute__((ext_vector_type(8)));
typedef float float4v __attribute__((ext_vector_type(4)));

// LDS map (bytes)
#define WRES_OFF  0                      // kk=0,1 resident: 128 KB
#define HF_OFF    131072                 // h, A-frag order: 16 KB
#define XS_OFF    147456                 // x[32 rows][32 steps] f32: 4 KB
#define LDS_TOTAL 151552

__device__ __forceinline__ float frcp(float v)  { return __builtin_amdgcn_rcpf(v); }
__device__ __forceinline__ float fex2(float v)  { return __builtin_amdgcn_exp2f(v); }
__device__ __forceinline__ float fsig(float v)  { return frcp(1.0f + fex2(-1.442695040888963f * v)); }
__device__ __forceinline__ float ftanh(float v) { return 2.0f * frcp(1.0f + fex2(-2.885390081777927f * v)) - 1.0f; }

#define BARRIER_LGKM() asm volatile("s_waitcnt lgkmcnt(0)\n\ts_barrier" ::: "memory")

// Pack W_{g,i,f,o}h (fp32 [256][256], row k, col j) into fp16 MFMA B-frag order.
// unit u = ((kk*16+s)*4+t)*64 + lane ; elem j: k = kk*32 + (lane>>4)*8 + j,
// gate t, hidden col j_h = s*16 + (lane&15).
__global__ void pack_weights(const float* __restrict__ Wg, const float* __restrict__ Wi,
                             const float* __restrict__ Wf, const float* __restrict__ Wo,
                             _Float16* __restrict__ wsW) {
    int u = blockIdx.x * blockDim.x + threadIdx.x;   // 32768 units
    int kk = u >> 12, rem = u & 4095;
    int s = rem >> 8, rem2 = rem & 255;
    int t = rem2 >> 6, lane = rem2 & 63;
    int q = lane >> 4, l15 = lane & 15;
    int jh = s * 16 + l15;
    const float* Wsrc = (t == 0) ? Wg : (t == 1) ? Wi : (t == 2) ? Wf : Wo;
    half8 v;
#pragma unroll
    for (int j = 0; j < 8; ++j) {
        int k = kk * 32 + q * 8 + j;
        v[j] = (_Float16)Wsrc[k * HH + jh];
    }
    ((half8*)wsW)[u] = v;
}

struct Grp { half8 f[2][4]; };   // one kk-group for one wave: 2 slices x 4 gates (32 VGPRs)

__device__ __forceinline__ void load_grp(Grp& B, const char* base) {
    // base = wsW + kk*65536 + s0*4096 + lane*16 ; offsets sp*4096 + t*1024
#pragma unroll
    for (int sp = 0; sp < 2; ++sp)
#pragma unroll
        for (int t = 0; t < 4; ++t)
            B.f[sp][t] = *(const half8*)(base + sp * 4096 + t * 1024);
}

__device__ __forceinline__ void mfma_grp(float4v acc[2][2][4], half8 a0, half8 a1, const Grp& B) {
#pragma unroll
    for (int sp = 0; sp < 2; ++sp)
#pragma unroll
        for (int t = 0; t < 4; ++t) {
            acc[0][sp][t] = __builtin_amdgcn_mfma_f32_16x16x32_f16(a0, B.f[sp][t], acc[0][sp][t], 0, 0, 0);
            acc[1][sp][t] = __builtin_amdgcn_mfma_f32_16x16x32_f16(a1, B.f[sp][t], acc[1][sp][t], 0, 0, 0);
        }
}

__attribute__((amdgpu_waves_per_eu(2, 2)))
__global__ void __launch_bounds__(512) lstm_main(
    const float* __restrict__ x, const _Float16* __restrict__ wsW,
    const float* __restrict__ Wgx, const float* __restrict__ Wix,
    const float* __restrict__ Wfx, const float* __restrict__ Wox,
    const float* __restrict__ bg, const float* __restrict__ bi,
    const float* __restrict__ bfp, const float* __restrict__ bo,
    const float* __restrict__ Wp, const float* __restrict__ bp,
    float* __restrict__ out)
{
    extern __shared__ char smem[];
    char*     WldsC = smem + WRES_OFF;
    _Float16* hf    = (_Float16*)(smem + HF_OFF);
    float*    xsL   = (float*)(smem + XS_OFF);

    const int tid  = threadIdx.x;
    const int wv   = tid >> 6;          // wave 0..7
    const int lane = tid & 63;
    const int q    = lane >> 4;
    const int l15  = lane & 15;
    const int s0   = wv * 2;            // this wave's first col-slice
    const int b0   = blockIdx.x * 32;

    // ---- prologue ----
    for (int i = tid; i < 8192; i += 512) hf[i] = (_Float16)0.f;    // h0 = 0
    {   // stage kk=0,1 into LDS (frag layout preserved)
        const uint4* src = (const uint4*)wsW;
        uint4* dst = (uint4*)WldsC;
        for (int i = tid; i < 131072 / 16; i += 512) dst[i] = src[i];
    }
    // per-lane bias / x-weight for owned cols jj=(s0+sp)*16+l15 (16 regs)
    float bv[2][4], wxv[2][4];
    {
        const float* bptr[4] = { bg, bi, bfp, bo };
        const float* wptr[4] = { Wgx, Wix, Wfx, Wox };
#pragma unroll
        for (int sp = 0; sp < 2; ++sp) {
            int jj = (s0 + sp) * 16 + l15;
#pragma unroll
            for (int t = 0; t < 4; ++t) { bv[sp][t] = bptr[t][jj]; wxv[sp][t] = wptr[t][jj]; }
        }
    }
    const char* wl = (const char*)wsW + s0 * 4096 + lane * 16;  // + kk*65536 + sp*4096 + t*1024
    Grp sbA, sbB;                       // reg stream ping-pong (64 VGPRs)
    load_grp(sbA, wl + 2 * 65536);      // prime: kk=2 in flight across prologue

    float4v cst[2][2];
#pragma unroll
    for (int mt = 0; mt < 2; ++mt)
#pragma unroll
        for (int sp = 0; sp < 2; ++sp) cst[mt][sp] = (float4v){0.f, 0.f, 0.f, 0.f};

    // h-write scatter base (A-frag order): col j = 32wv+sp*16+l15, row mt*16+q*4+r
    const int wb = wv * 512 + ((l15 >> 3) * 16 + q * 4) * 8 + (l15 & 7);  // + mt*4096 + sp*256 + r*8

    __syncthreads();

#define AREAD(kkv, mtv) (*(const half8*)(hf + (mtv) * 4096 + (kkv) * 512 + lane * 8))

    // ---- time loop ----
#pragma unroll 1
    for (int ts = 0; ts < TT; ++ts) {
        // x staging: once per 32 steps (vmcnt drain here is rare/amortized)
        if ((ts & 31) == 0) {
            const int row = tid >> 4;            // 0..31
            const int c2  = (tid & 15) * 2;      // 0,2,..,30
            float2 xv2 = *(const float2*)&x[(b0 + row) * TT + ts + c2];
            *(float2*)&xsL[row * 32 + c2] = xv2;
            BARRIER_LGKM();
        }

        // step-entry: issue sbB <- kk=3 (consumed after kk=0,1,2 ~ covered)
        load_grp(sbB, wl + 3 * 65536);

        // acc init = bias + x_t * W_x (fp32, exact)
        float xv[2][4];
#pragma unroll
        for (int mt = 0; mt < 2; ++mt)
#pragma unroll
            for (int r = 0; r < 4; ++r)
                xv[mt][r] = xsL[(mt * 16 + q * 4 + r) * 32 + (ts & 31)];
        float4v acc[2][2][4];
#pragma unroll
        for (int mt = 0; mt < 2; ++mt)
#pragma unroll
            for (int sp = 0; sp < 2; ++sp)
#pragma unroll
                for (int t = 0; t < 4; ++t)
#pragma unroll
                    for (int r = 0; r < 4; ++r)
                        acc[mt][sp][t][r] = bv[sp][t] + xv[mt][r] * wxv[sp][t];

        half8 a0, a1;
        // kk=0,1: B from LDS resident (covers sbB latency)
#pragma unroll
        for (int kk = 0; kk < 2; ++kk) {
            a0 = AREAD(kk, 0); a1 = AREAD(kk, 1);
            const char* lb = WldsC + kk * 65536 + s0 * 4096 + lane * 16;
#pragma unroll
            for (int sp = 0; sp < 2; ++sp)
#pragma unroll
                for (int t = 0; t < 4; ++t) {
                    half8 bf = *(const half8*)(lb + sp * 4096 + t * 1024);
                    acc[0][sp][t] = __builtin_amdgcn_mfma_f32_16x16x32_f16(a0, bf, acc[0][sp][t], 0, 0, 0);
                    acc[1][sp][t] = __builtin_amdgcn_mfma_f32_16x16x32_f16(a1, bf, acc[1][sp][t], 0, 0, 0);
                }
        }
        // kk=2..7: reg-streamed; consume then reissue. Only sbA's next-step
        // load stays in flight across the gate phase (sbB dead there).
        a0 = AREAD(2, 0); a1 = AREAD(2, 1); mfma_grp(acc, a0, a1, sbA);
        load_grp(sbA, wl + 4 * 65536);
        a0 = AREAD(3, 0); a1 = AREAD(3, 1); mfma_grp(acc, a0, a1, sbB);
        load_grp(sbB, wl + 5 * 65536);
        a0 = AREAD(4, 0); a1 = AREAD(4, 1); mfma_grp(acc, a0, a1, sbA);
        load_grp(sbA, wl + 6 * 65536);
        a0 = AREAD(5, 0); a1 = AREAD(5, 1); mfma_grp(acc, a0, a1, sbB);
        load_grp(sbB, wl + 7 * 65536);
        a0 = AREAD(6, 0); a1 = AREAD(6, 1); mfma_grp(acc, a0, a1, sbA);
        load_grp(sbA, wl + 2 * 65536);     // next step's kk=2 (in flight over gates)
        a0 = AREAD(7, 0); a1 = AREAD(7, 1); mfma_grp(acc, a0, a1, sbB);

        // gates + state update (lane owns rows mt*16+q*4+r, col (s0+sp)*16+l15)
        _Float16 hn[2][2][4];
#pragma unroll
        for (int mt = 0; mt < 2; ++mt)
#pragma unroll
            for (int sp = 0; sp < 2; ++sp)
#pragma unroll
                for (int r = 0; r < 4; ++r) {
                    float g  = ftanh(acc[mt][sp][0][r]);
                    float ii = fsig (acc[mt][sp][1][r]);
                    float f  = fsig (acc[mt][sp][2][r]);
                    float o  = fsig (acc[mt][sp][3][r]);
                    float cn = g * ii + cst[mt][sp][r] * f;
                    cst[mt][sp][r] = cn;
                    hn[mt][sp][r] = (_Float16)(ftanh(cn) * o);
                }

        BARRIER_LGKM();   // B1: all waves' LDS reads of this step retired
#pragma unroll
        for (int mt = 0; mt < 2; ++mt)
#pragma unroll
            for (int sp = 0; sp < 2; ++sp)
#pragma unroll
                for (int r = 0; r < 4; ++r)
                    hf[mt * 4096 + wb + sp * 256 + r * 8] = hn[mt][sp][r];
        BARRIER_LGKM();   // B2: new h visible; sbA's global loads stay in flight
    }

    // ---- epilogue: out = h_T @ W_ph + b_p ; wave wv handles rows 4wv..4wv+3 ----
#pragma unroll
    for (int rr = 0; rr < 4; ++rr) {
        int b = wv * 4 + rr;
        int mt = b >> 4, m = b & 15;
        float hv[4];
#pragma unroll
        for (int a = 0; a < 4; ++a) {
            int j = lane + a * 64;
            int idx = mt * 4096 + (j >> 5) * 512 + (((j >> 3) & 3) * 16 + m) * 8 + (j & 7);
            hv[a] = (float)hf[idx];
        }
#pragma unroll
        for (int c = 0; c < CC; ++c) {
            float sacc = 0.f;
#pragma unroll
            for (int a = 0; a < 4; ++a) sacc += hv[a] * Wp[(lane + a * 64) * CC + c];
#pragma unroll
            for (int off = 32; off > 0; off >>= 1) sacc += __shfl_xor(sacc, off, 64);
            if (lane == 0) out[(b0 + b) * CC + c] = sacc + bp[c];
        }
    }
}

extern "C" void kernel_launch(void* const* d_in, const int* in_sizes, int n_in,
                              void* d_out, int out_size, void* d_ws, size_t ws_size,
                              hipStream_t stream) {
    (void)in_sizes; (void)n_in; (void)out_size; (void)ws_size; // needs ws_size >= 524288
    const float* x   = (const float*)d_in[0];
    const float* Wgx = (const float*)d_in[1];
    const float* Wgh = (const float*)d_in[2];
    const float* Wix = (const float*)d_in[3];
    const float* Wih = (const float*)d_in[4];
    const float* Wfx = (const float*)d_in[5];
    const float* Wfh = (const float*)d_in[6];
    const float* Wox = (const float*)d_in[7];
    const float* Woh = (const float*)d_in[8];
    const float* Wp  = (const float*)d_in[9];
    const float* bg  = (const float*)d_in[10];
    const float* bi  = (const float*)d_in[11];
    const float* bf  = (const float*)d_in[12];
    const float* bo  = (const float*)d_in[13];
    const float* bp  = (const float*)d_in[14];
    _Float16* wsW = (_Float16*)d_ws;

    pack_weights<<<128, 256, 0, stream>>>(Wgh, Wih, Wfh, Woh, wsW);

    hipFuncSetAttribute((const void*)lstm_main,
                        hipFuncAttributeMaxDynamicSharedMemorySize, LDS_TOTAL);
    lstm_main<<<256, 512, LDS_TOTAL, stream>>>(
        x, wsW, Wgx, Wix, Wfx, Wox, bg, bi, bf, bo, Wp, bp, (float*)d_out);
}